// Round 11
// baseline (31640.146 us; speedup 1.0000x reference)
//
#include <hip/hip_runtime.h>
#include <cstdint>
#include <cstddef>

#define T_STEPS 1024
#define NB 64
#define DIN 256
#define DH 256
#define DW 512            // DIN + DH (row width of each W)
#define G4 1024           // 4*DH gate rows

typedef _Float16 h2 __attribute__((ext_vector_type(2)));
typedef _Float16 h4 __attribute__((ext_vector_type(4)));
typedef _Float16 h8 __attribute__((ext_vector_type(8)));
typedef float f4 __attribute__((ext_vector_type(4)));

static __device__ __forceinline__ h2 sl2(h8 v, int m) {
  h2 r; r[0] = v[2 * m]; r[1] = v[2 * m + 1]; return r;
}
static __device__ __forceinline__ h2 sl2_4(h4 v, int m) {
  h2 r; r[0] = v[2 * m]; r[1] = v[2 * m + 1]; return r;
}

static __device__ __forceinline__ float fdot2(h2 a, h2 b, float c) {
#if __has_builtin(__builtin_amdgcn_fdot2)
  return __builtin_amdgcn_fdot2(a, b, c, false);
#else
  return c + (float)a[0]*(float)b[0] + (float)a[1]*(float)b[1];
#endif
}

static __device__ __forceinline__ float rcp_(float x) {
#if __has_builtin(__builtin_amdgcn_rcpf)
  return __builtin_amdgcn_rcpf(x);
#else
  return 1.0f / x;
#endif
}

static __device__ __forceinline__ float sigmoid_(float x) {
  return rcp_(1.f + __expf(-x));
}
static __device__ __forceinline__ float tanh_(float x) {
  float e = __expf(2.f * x);
  return 1.f - 2.f * rcp_(e + 1.f);
}

// DPP quad-perm swaps: xor-1 ([1,0,3,2]=0xB1) and xor-2 ([2,3,0,1]=0x4E).
static __device__ __forceinline__ float dpp_swap1(float x) {
  int r = __builtin_amdgcn_update_dpp(0, __builtin_bit_cast(int, x),
                                      0xB1, 0xF, 0xF, true);
  return __builtin_bit_cast(float, r);
}
static __device__ __forceinline__ float dpp_swap2(float x) {
  int r = __builtin_amdgcn_update_dpp(0, __builtin_bit_cast(int, x),
                                      0x4E, 0xF, 0xF, true);
  return __builtin_bit_cast(float, r);
}

// ---------------------------------------------------------------------------
// Weight pre-conversion (unchanged).
// ---------------------------------------------------------------------------
__global__ void kconv_w(const float* __restrict__ Wf, const float* __restrict__ Wi,
                        const float* __restrict__ Wg, const float* __restrict__ Wo,
                        h2* __restrict__ wxhT, h2* __restrict__ wrowh) {
  int kp = blockIdx.x >> 2;
  int gate = blockIdx.x & 3;
  int j = threadIdx.x;
  const float* W = gate == 0 ? Wf : gate == 1 ? Wi : gate == 2 ? Wg : Wo;
  const float* row = W + (size_t)j * DW;
  h2 v; v[0] = (_Float16)row[2*kp]; v[1] = (_Float16)row[2*kp + 1];
  wxhT[(size_t)kp * G4 + gate * DH + j] = v;
  h2 u; u[0] = (_Float16)row[DIN + 2*kp]; u[1] = (_Float16)row[DIN + 2*kp + 1];
  wrowh[((size_t)gate * DH + j) * 128 + kp] = u;
}

// ---------------------------------------------------------------------------
// Phase 1: Xg[t][b][gr] = x[t][b][:] . Wx[gr][:] + bias[gr]   (f16 out)
// (unchanged)
// ---------------------------------------------------------------------------
__launch_bounds__(256, 2)
__global__ void kxgemm(const float* __restrict__ x,
                       const h2* __restrict__ wxhT,
                       const float* __restrict__ bf, const float* __restrict__ bi,
                       const float* __restrict__ bg, const float* __restrict__ bo,
                       _Float16* __restrict__ Xg,
                       int t0) {
  __shared__ h2 xs[64 * 64];
  __shared__ h2 wsT[64 * 256];

  int tid = threadIdx.x;
  int tg = tid & 31, tr = tid >> 5;
  int tb = blockIdx.x >> 2, gb = blockIdx.x & 3;
  size_t xrow0 = ((size_t)(t0 + tb)) * NB;

  float acc[8][8];
#pragma unroll
  for (int r = 0; r < 8; ++r)
#pragma unroll
    for (int g = 0; g < 8; ++g) acc[r][g] = 0.f;

  for (int ks = 0; ks < 2; ++ks) {
#pragma unroll
    for (int i = 0; i < 8; ++i) {
      int idx = tid + 256 * i;
      int r = idx >> 5, k4 = idx & 31;
      f4 v = *(const f4*)(x + (xrow0 + r) * DIN + ks * 128 + k4 * 4);
      h4 p;
      p[0] = (_Float16)v[0]; p[1] = (_Float16)v[1];
      p[2] = (_Float16)v[2]; p[3] = (_Float16)v[3];
      *(h4*)(void*)(xs + (size_t)r * 64 + 2 * k4) = p;
    }
#pragma unroll
    for (int i = 0; i < 16; ++i) {
      int idx = tid + 256 * i;
      int kp = idx >> 6, g4 = idx & 63;
      f4 v = *(const f4*)(const void*)(wxhT + (size_t)(ks * 64 + kp) * G4 + gb * DH + g4 * 4);
      *(f4*)(void*)(wsT + (size_t)kp * 256 + g4 * 4) = v;
    }
    __syncthreads();

#pragma unroll 2
    for (int kp2 = 0; kp2 < 32; ++kp2) {
      h4 xv[8];
#pragma unroll
      for (int r = 0; r < 8; ++r)
        xv[r] = *(const h4*)(const void*)(xs + (size_t)(tr * 8 + r) * 64 + 2 * kp2);
      h8 w0a = *(const h8*)(const void*)(wsT + (size_t)(2 * kp2) * 256 + tg * 8);
      h8 w0b = *(const h8*)(const void*)(wsT + (size_t)(2 * kp2) * 256 + tg * 8 + 4);
      h8 w1a = *(const h8*)(const void*)(wsT + (size_t)(2 * kp2 + 1) * 256 + tg * 8);
      h8 w1b = *(const h8*)(const void*)(wsT + (size_t)(2 * kp2 + 1) * 256 + tg * 8 + 4);
#pragma unroll
      for (int r = 0; r < 8; ++r) {
        h2 x0 = sl2_4(xv[r], 0);
        h2 x1 = sl2_4(xv[r], 1);
#pragma unroll
        for (int g = 0; g < 4; ++g) {
          acc[r][g] = fdot2(x0, sl2(w0a, g), acc[r][g]);
          acc[r][g] = fdot2(x1, sl2(w1a, g), acc[r][g]);
        }
#pragma unroll
        for (int g = 0; g < 4; ++g) {
          acc[r][4 + g] = fdot2(x0, sl2(w0b, g), acc[r][4 + g]);
          acc[r][4 + g] = fdot2(x1, sl2(w1b, g), acc[r][4 + g]);
        }
      }
    }
    __syncthreads();
  }

  const float* bias = gb == 0 ? bf : gb == 1 ? bi : gb == 2 ? bg : bo;
  float bv[8];
#pragma unroll
  for (int g = 0; g < 8; ++g) bv[g] = bias[tg * 8 + g];
#pragma unroll
  for (int r = 0; r < 8; ++r) {
    h8 o;
#pragma unroll
    for (int g = 0; g < 8; ++g) o[g] = (_Float16)(acc[r][g] + bv[g]);
    *(h8*)(void*)(Xg + ((size_t)tb * NB + tr * 8 + r) * G4 + gb * DH + tg * 8) = o;
  }
}

// ---------------------------------------------------------------------------
// Phase 2: sequential LSTM, 4 BLOCKS PER BATCH ELEMENT.
// Grid 256 = (q = bid>>6 unit-quarter, b = bid&63): partners of a batch share
// an XCD (bid%8 == b%8). Block owns units j in [64q, 64q+64).
// 256 threads: u = tid>>2 (unit-local), p = tid&3 (K-quarter).
// Thread holds ALL 4 gate rows of unit j over K-quarter p: 32 h8 = 128 VGPRs,
// fully register-resident (grant at 256 threads = 256 VGPRs; r2-r10 rule).
// ZERO weight-LDS. K-quarter partials summed via 2-stage DPP butterfly.
// Per-step cross-block h-exchange: double-buffered hx (f32, relaxed-agent
// atomics) + monotonic flags (release/acquire, agent). 90KB LDS pad forces
// 1 block/CU -> all 256 blocks co-resident (no spin deadlock), 256 CUs busy.
// ---------------------------------------------------------------------------
#define CH8(M) M(0) M(1) M(2) M(3) M(4) M(5) M(6) M(7)
#define HQ 36   // h2 stride of one h-quarter in hbuf (32 + 4 skew)

__global__ __launch_bounds__(256, 1)
void klstm(const h2* __restrict__ wrowh,
           const _Float16* __restrict__ Xg,
           const float* __restrict__ hsrc, const float* __restrict__ csrc,
           float* __restrict__ out,
           float* __restrict__ hN, float* __restrict__ cN,
           float* __restrict__ hx, unsigned* __restrict__ flag,
           int t0, int Tc) {
  __shared__ h2 hbuf[2][4 * HQ];   // double-buffered h (f16), quarters skewed
  __shared__ char pad[90112];      // occupancy limiter: 1 block/CU

  int tid = threadIdx.x;
  int bq = blockIdx.x;
  int b = bq & 63;
  int q = bq >> 6;
  int p = tid & 3;
  int u = tid >> 2;
  int j = q * 64 + u;

  pad[tid] = (char)tid;  // keep pad allocated (never read)

  const h2* rowF = wrowh + ((size_t)(0 * DH + j)) * 128 + p * 32;
  const h2* rowI = wrowh + ((size_t)(1 * DH + j)) * 128 + p * 32;
  const h2* rowG = wrowh + ((size_t)(2 * DH + j)) * 128 + p * 32;
  const h2* rowO = wrowh + ((size_t)(3 * DH + j)) * 128 + p * 32;

  // --- weights: 8 h8 chunks per gate row, all in named registers ---
#define DECLW(c) h8 WF_##c, WI_##c, WG_##c, WO_##c;
  CH8(DECLW)
#undef DECLW
#define LOADW(c) \
  WF_##c = *(const h8*)(const void*)(rowF + 4 * (c)); \
  WI_##c = *(const h8*)(const void*)(rowI + 4 * (c)); \
  WG_##c = *(const h8*)(const void*)(rowG + 4 * (c)); \
  WO_##c = *(const h8*)(const void*)(rowO + 4 * (c));
  CH8(LOADW)
#undef LOADW
#define PINW(c) \
  asm volatile("" : "+v"(WF_##c)); asm volatile("" : "+v"(WI_##c)); \
  asm volatile("" : "+v"(WG_##c)); asm volatile("" : "+v"(WO_##c));
  CH8(PINW)
#undef PINW

  float creg = csrc[(size_t)b * DH + j];  // replicated across the quad
  if (tid < 128) {
    // h2 element pair (2*tid, 2*tid+1): quarter qh = tid>>5, skewed pos
    int pos = (tid >> 5) * HQ + (tid & 31);
    h2 hv;
    hv[0] = (_Float16)hsrc[(size_t)b * DH + 2 * tid];
    hv[1] = (_Float16)hsrc[(size_t)b * DH + 2 * tid + 1];
    hbuf[0][pos] = hv;
  }
  __syncthreads();

  const size_t xstep = (size_t)NB * G4;
  const _Float16* xp = Xg + (size_t)b * G4 + p * DH + j;  // gate p's x-row
  float xcur = (float)xp[0];
  float hlast = 0.f;

  int fo1 = b * 4 + ((q + 1) & 3);
  int fo2 = b * 4 + ((q + 2) & 3);
  int fo3 = b * 4 + ((q + 3) & 3);

  for (int t = 0; t < Tc; ++t) {
    float xnext = (t + 1 < Tc) ? (float)xp[(size_t)(t + 1) * xstep] : 0.f;
    const h2* hb = hbuf[t & 1] + p * HQ;

    // x counted once per gate across the quad: lane p seeds gate p
    float accF = (p == 0) ? xcur : 0.f;
    float accI = (p == 1) ? xcur : 0.f;
    float accG = (p == 2) ? xcur : 0.f;
    float accO = (p == 3) ? xcur : 0.f;

#define DOTCH(c) { \
    h8 hv = *(const h8*)(const void*)(hb + 4 * (c)); \
    accF = fdot2(sl2(WF_##c,0), sl2(hv,0), accF); \
    accF = fdot2(sl2(WF_##c,1), sl2(hv,1), accF); \
    accF = fdot2(sl2(WF_##c,2), sl2(hv,2), accF); \
    accF = fdot2(sl2(WF_##c,3), sl2(hv,3), accF); \
    accI = fdot2(sl2(WI_##c,0), sl2(hv,0), accI); \
    accI = fdot2(sl2(WI_##c,1), sl2(hv,1), accI); \
    accI = fdot2(sl2(WI_##c,2), sl2(hv,2), accI); \
    accI = fdot2(sl2(WI_##c,3), sl2(hv,3), accI); \
    accG = fdot2(sl2(WG_##c,0), sl2(hv,0), accG); \
    accG = fdot2(sl2(WG_##c,1), sl2(hv,1), accG); \
    accG = fdot2(sl2(WG_##c,2), sl2(hv,2), accG); \
    accG = fdot2(sl2(WG_##c,3), sl2(hv,3), accG); \
    accO = fdot2(sl2(WO_##c,0), sl2(hv,0), accO); \
    accO = fdot2(sl2(WO_##c,1), sl2(hv,1), accO); \
    accO = fdot2(sl2(WO_##c,2), sl2(hv,2), accO); \
    accO = fdot2(sl2(WO_##c,3), sl2(hv,3), accO); }
    CH8(DOTCH)
#undef DOTCH

    // sum K-quarter partials across the quad: 2-stage DPP butterfly ->
    // ALL 4 lanes hold the full f,i,g,o sums (x included exactly once).
    accF += dpp_swap1(accF); accI += dpp_swap1(accI);
    accG += dpp_swap1(accG); accO += dpp_swap1(accO);
    accF += dpp_swap2(accF); accI += dpp_swap2(accI);
    accG += dpp_swap2(accG); accO += dpp_swap2(accO);

    float f_ = sigmoid_(accF);
    float i_ = sigmoid_(accI);
    float g_ = tanh_(accG);
    float o_ = sigmoid_(accO);

    creg = f_ * creg + i_ * g_;
    float hn = o_ * tanh_(creg);
    hlast = hn;

    int nxt = (t + 1) & 1;
    if (p == 0) {
      out[((size_t)(t0 + t) * NB + b) * DH + j] = hn;
    } else if (p == 1) {
      ((_Float16*)hbuf[nxt])[q * 72 + u] = (_Float16)hn;  // own quarter, skewed
    } else if (p == 2 && t + 1 < Tc) {
      __hip_atomic_store(&hx[(size_t)nxt * 16384 + b * 256 + j], hn,
                         __ATOMIC_RELAXED, __HIP_MEMORY_SCOPE_AGENT);
    }
    __syncthreads();  // drains all stores (vmcnt 0) before flag release

    if (t + 1 < Tc) {
      unsigned tgt = (unsigned)(t + 1);
      if (tid == 0)
        __hip_atomic_store(&flag[bq & 255 ? b * 4 + q : b * 4 + q], tgt,
                           __ATOMIC_RELEASE, __HIP_MEMORY_SCOPE_AGENT);
      // poll the 3 partner quarters
      while (__hip_atomic_load(&flag[fo1], __ATOMIC_ACQUIRE, __HIP_MEMORY_SCOPE_AGENT) < tgt ||
             __hip_atomic_load(&flag[fo2], __ATOMIC_ACQUIRE, __HIP_MEMORY_SCOPE_AGENT) < tgt ||
             __hip_atomic_load(&flag[fo3], __ATOMIC_ACQUIRE, __HIP_MEMORY_SCOPE_AGENT) < tgt) {
      }
      // stage the 3 partner quarters into hbuf[nxt]
      if (tid < 192) {
        int pi = tid >> 6;                 // 0..2
        int pq = (q + 1 + pi) & 3;         // partner quarter
        int idx = tid & 63;
        float v = __hip_atomic_load(&hx[(size_t)nxt * 16384 + b * 256 + pq * 64 + idx],
                                    __ATOMIC_RELAXED, __HIP_MEMORY_SCOPE_AGENT);
        ((_Float16*)hbuf[nxt])[pq * 72 + idx] = (_Float16)v;
      }
      __syncthreads();
    }
    xcur = xnext;
  }

  if (p == 0) {
    hN[(size_t)b * DH + j] = hlast;
    cN[(size_t)b * DH + j] = creg;
  }
}

// ---------------------------------------------------------------------------
extern "C" void kernel_launch(void* const* d_in, const int* in_sizes, int n_in,
                              void* d_out, int out_size, void* d_ws, size_t ws_size,
                              hipStream_t stream) {
  if (n_in < 11) return;
  const float* x  = (const float*)d_in[0];
  const float* h0 = (const float*)d_in[1];
  const float* c0 = (const float*)d_in[2];
  const float* Wf = (const float*)d_in[3];
  const float* bf = (const float*)d_in[4];
  const float* Wi = (const float*)d_in[5];
  const float* bi = (const float*)d_in[6];
  const float* Wg = (const float*)d_in[7];
  const float* bg = (const float*)d_in[8];
  const float* Wo = (const float*)d_in[9];
  const float* bo = (const float*)d_in[10];

  float* out = (float*)d_out;
  float* hN = out + (size_t)T_STEPS * NB * DH;
  float* cN = hN + (size_t)NB * DH;

  // ws layout: [Xg: Tc*128KB][wxhT 512KB][wrowh 512KB][hx 128KB][flags 1KB]
  const size_t wxhBytes  = (size_t)128 * G4 * sizeof(h2);   // 512KB
  const size_t wrowBytes = (size_t)G4 * 128 * sizeof(h2);   // 512KB
  const size_t hxBytes   = (size_t)2 * NB * DH * sizeof(float);  // 128KB
  const size_t flagBytes = 256 * sizeof(unsigned);
  const size_t fixedBytes = wxhBytes + wrowBytes + hxBytes + flagBytes;
  size_t avail = (ws_size > fixedBytes + 512) ? ws_size - fixedBytes - 512 : 0;
  const size_t perT = (size_t)NB * G4 * 2;  // 128KB per time step
  int Tc = (int)(avail / perT);
  if (Tc > T_STEPS) Tc = T_STEPS;
  if (Tc < 1) Tc = 1;

  _Float16* Xg = (_Float16*)d_ws;
  size_t xgBytes = ((size_t)Tc * perT + 255) / 256 * 256;
  h2* wxhT  = (h2*)((char*)d_ws + xgBytes);
  h2* wrowh = (h2*)((char*)d_ws + xgBytes + wxhBytes);
  float* hx = (float*)((char*)d_ws + xgBytes + wxhBytes + wrowBytes);
  unsigned* flags = (unsigned*)((char*)d_ws + xgBytes + wxhBytes + wrowBytes + hxBytes);

  kconv_w<<<dim3(512), dim3(256), 0, stream>>>(Wf, Wi, Wg, Wo, wxhT, wrowh);

  for (int t0 = 0; t0 < T_STEPS; t0 += Tc) {
    int tc = (T_STEPS - t0 < Tc) ? (T_STEPS - t0) : Tc;
    kxgemm<<<dim3(tc * 4), dim3(256), 0, stream>>>(x, wxhT, bf, bi, bg, bo, Xg, t0);
    hipMemsetAsync(flags, 0, flagBytes, stream);
    const float* hs = (t0 == 0) ? h0 : hN;
    const float* cs = (t0 == 0) ? c0 : cN;
    klstm<<<dim3(256), dim3(256), 0, stream>>>(wrowh, Xg, hs, cs,
                                               out, hN, cN, hx, flags, t0, tc);
  }
}

// Round 12
// 3200.283 us; speedup vs baseline: 9.8867x; 9.8867x over previous
//
#include <hip/hip_runtime.h>
#include <cstdint>
#include <cstddef>

#define T_STEPS 1024
#define NB 64
#define DIN 256
#define DH 256
#define DW 512            // DIN + DH (row width of each W)
#define G4 1024           // 4*DH gate rows

typedef _Float16 h2 __attribute__((ext_vector_type(2)));
typedef _Float16 h4 __attribute__((ext_vector_type(4)));
typedef _Float16 h8 __attribute__((ext_vector_type(8)));
typedef float f4 __attribute__((ext_vector_type(4)));

static __device__ __forceinline__ h2 sl2(h8 v, int m) {
  h2 r; r[0] = v[2 * m]; r[1] = v[2 * m + 1]; return r;
}
static __device__ __forceinline__ h2 sl2_4(h4 v, int m) {
  h2 r; r[0] = v[2 * m]; r[1] = v[2 * m + 1]; return r;
}

static __device__ __forceinline__ float fdot2(h2 a, h2 b, float c) {
#if __has_builtin(__builtin_amdgcn_fdot2)
  return __builtin_amdgcn_fdot2(a, b, c, false);
#else
  return c + (float)a[0]*(float)b[0] + (float)a[1]*(float)b[1];
#endif
}

static __device__ __forceinline__ float rcp_(float x) {
#if __has_builtin(__builtin_amdgcn_rcpf)
  return __builtin_amdgcn_rcpf(x);
#else
  return 1.0f / x;
#endif
}

static __device__ __forceinline__ float sigmoid_(float x) {
  return rcp_(1.f + __expf(-x));
}
static __device__ __forceinline__ float tanh_(float x) {
  float e = __expf(2.f * x);
  return 1.f - 2.f * rcp_(e + 1.f);
}

// Pairwise lane swap (0<->1, ...) via DPP quad_perm [1,0,3,2] — pure VALU.
static __device__ __forceinline__ float dpp_swap1(float x) {
  int r = __builtin_amdgcn_update_dpp(0, __builtin_bit_cast(int, x),
                                      0xB1, 0xF, 0xF, true);
  return __builtin_bit_cast(float, r);
}

// ---------------------------------------------------------------------------
// Weight pre-conversion.
//  wxhT[kp][gr]   x-part, k-pair-major        (kxgemm)
//  wrowh[gr][kp]  h-part, row-major           (klstm resident chunks 0..3)
//  wstr[c-4][gr][2j+p]  h-part streaming layout (klstm chunks 4..15):
//    h8-index = (c-4)*2048 + gate*512 + 2j + p  -> lane-consecutive 16B
//    (coalesced: one wave-inst reads 1KB contiguous)
// ---------------------------------------------------------------------------
__global__ void kconv_w(const float* __restrict__ Wf, const float* __restrict__ Wi,
                        const float* __restrict__ Wg, const float* __restrict__ Wo,
                        h2* __restrict__ wxhT, h2* __restrict__ wrowh,
                        h2* __restrict__ wstr) {
  int kp = blockIdx.x >> 2;
  int gate = blockIdx.x & 3;
  int j = threadIdx.x;
  const float* W = gate == 0 ? Wf : gate == 1 ? Wi : gate == 2 ? Wg : Wo;
  const float* row = W + (size_t)j * DW;
  h2 v; v[0] = (_Float16)row[2*kp]; v[1] = (_Float16)row[2*kp + 1];
  wxhT[(size_t)kp * G4 + gate * DH + j] = v;
  h2 u; u[0] = (_Float16)row[DIN + 2*kp]; u[1] = (_Float16)row[DIN + 2*kp + 1];
  wrowh[((size_t)gate * DH + j) * 128 + kp] = u;
  // streaming layout for chunks 4..15
  int p = kp >> 6;          // K-half
  int kpl = kp & 63;        // within-half h2 index
  int c = kpl >> 2;         // chunk 0..15
  int slot = kpl & 3;
  if (c >= 4) {
    size_t h8idx = (size_t)(c - 4) * 2048 + (size_t)gate * 512 + 2 * j + p;
    wstr[h8idx * 4 + slot] = u;
  }
}

// ---------------------------------------------------------------------------
// Phase 1: Xg[t][b][gr] = x[t][b][:] . Wx[gr][:] + bias[gr]   (f16 out)
// (unchanged)
// ---------------------------------------------------------------------------
__launch_bounds__(256, 2)
__global__ void kxgemm(const float* __restrict__ x,
                       const h2* __restrict__ wxhT,
                       const float* __restrict__ bf, const float* __restrict__ bi,
                       const float* __restrict__ bg, const float* __restrict__ bo,
                       _Float16* __restrict__ Xg,
                       int t0) {
  __shared__ h2 xs[64 * 64];
  __shared__ h2 wsT[64 * 256];

  int tid = threadIdx.x;
  int tg = tid & 31, tr = tid >> 5;
  int tb = blockIdx.x >> 2, gb = blockIdx.x & 3;
  size_t xrow0 = ((size_t)(t0 + tb)) * NB;

  float acc[8][8];
#pragma unroll
  for (int r = 0; r < 8; ++r)
#pragma unroll
    for (int g = 0; g < 8; ++g) acc[r][g] = 0.f;

  for (int ks = 0; ks < 2; ++ks) {
#pragma unroll
    for (int i = 0; i < 8; ++i) {
      int idx = tid + 256 * i;
      int r = idx >> 5, k4 = idx & 31;
      f4 v = *(const f4*)(x + (xrow0 + r) * DIN + ks * 128 + k4 * 4);
      h4 pq;
      pq[0] = (_Float16)v[0]; pq[1] = (_Float16)v[1];
      pq[2] = (_Float16)v[2]; pq[3] = (_Float16)v[3];
      *(h4*)(void*)(xs + (size_t)r * 64 + 2 * k4) = pq;
    }
#pragma unroll
    for (int i = 0; i < 16; ++i) {
      int idx = tid + 256 * i;
      int kp = idx >> 6, g4 = idx & 63;
      f4 v = *(const f4*)(const void*)(wxhT + (size_t)(ks * 64 + kp) * G4 + gb * DH + g4 * 4);
      *(f4*)(void*)(wsT + (size_t)kp * 256 + g4 * 4) = v;
    }
    __syncthreads();

#pragma unroll 2
    for (int kp2 = 0; kp2 < 32; ++kp2) {
      h4 xv[8];
#pragma unroll
      for (int r = 0; r < 8; ++r)
        xv[r] = *(const h4*)(const void*)(xs + (size_t)(tr * 8 + r) * 64 + 2 * kp2);
      h8 w0a = *(const h8*)(const void*)(wsT + (size_t)(2 * kp2) * 256 + tg * 8);
      h8 w0b = *(const h8*)(const void*)(wsT + (size_t)(2 * kp2) * 256 + tg * 8 + 4);
      h8 w1a = *(const h8*)(const void*)(wsT + (size_t)(2 * kp2 + 1) * 256 + tg * 8);
      h8 w1b = *(const h8*)(const void*)(wsT + (size_t)(2 * kp2 + 1) * 256 + tg * 8 + 4);
#pragma unroll
      for (int r = 0; r < 8; ++r) {
        h2 x0 = sl2_4(xv[r], 0);
        h2 x1 = sl2_4(xv[r], 1);
#pragma unroll
        for (int g = 0; g < 4; ++g) {
          acc[r][g] = fdot2(x0, sl2(w0a, g), acc[r][g]);
          acc[r][g] = fdot2(x1, sl2(w1a, g), acc[r][g]);
        }
#pragma unroll
        for (int g = 0; g < 4; ++g) {
          acc[r][4 + g] = fdot2(x0, sl2(w0b, g), acc[r][4 + g]);
          acc[r][4 + g] = fdot2(x1, sl2(w1b, g), acc[r][4 + g]);
        }
      }
    }
    __syncthreads();
  }

  const float* bias = gb == 0 ? bf : gb == 1 ? bi : gb == 2 ? bg : bo;
  float bv[8];
#pragma unroll
  for (int g = 0; g < 8; ++g) bv[g] = bias[tg * 8 + g];
#pragma unroll
  for (int r = 0; r < 8; ++r) {
    h8 o;
#pragma unroll
    for (int g = 0; g < 8; ++g) o[g] = (_Float16)(acc[r][g] + bv[g]);
    *(h8*)(void*)(Xg + ((size_t)tb * NB + tr * 8 + r) * G4 + gb * DH + tg * 8) = o;
  }
}

// ---------------------------------------------------------------------------
// Phase 2: sequential LSTM. One workgroup per batch (sync-free), 512 threads.
// Thread (j = tid>>1, p = tid&1), all 4 gate rows of unit j over its K-half.
// PIPE REBALANCE (r12): r2-r9 invariance traced to 256 ds_read_b128/CU/step
// (~3070 cyc LDS-pipe wall). Now:
//   chunks 0..3  (16 h8 = 64 regs) resident in arch VGPRs (honest vs the
//                immovable 128-VGPR grant)
//   chunks 4..15 STREAMED from L2 each step via coalesced wstr layout
//                (VMEM pipe — idle until now), A/B double-buffered
//   LDS carries ONLY h: 16 reads/thread/step (128 insts/CU ~ 1536 cyc)
// hbuf inside an 84KB referenced static LDS pool -> 1 block/CU, 64 CUs busy.
// ---------------------------------------------------------------------------
#define CHR(M) M(0) M(1) M(2) M(3)
#define HPAD 68   // h2 stride of one K-half in hbuf (64 + 4 skew)

__global__ __launch_bounds__(512, 1)
void klstm(const h2* __restrict__ wrowh,
           const h8* __restrict__ wstr,
           const _Float16* __restrict__ Xg,
           const float* __restrict__ hsrc, const float* __restrict__ csrc,
           float* __restrict__ out,
           float* __restrict__ hN, float* __restrict__ cN,
           int t0, int Tc) {
  // 84KB pool; hbuf occupies the head, rest enforces 1 block/CU (object is
  // referenced, so it cannot be eliminated like r11's dead pad).
  __shared__ h2 hpool[2][10752];   // 2*10752*4B = 86016B

  int tid = threadIdx.x;
  int b = blockIdx.x;
  int p = tid & 1;
  int j = tid >> 1;
  int hoff = p * HPAD;

  h2* hbuf0 = hpool[0];
  h2* hbuf1 = hpool[1];

  const h2* rowF = wrowh + ((size_t)0 * DH + j) * 128 + p * 64;
  const h2* rowI = wrowh + ((size_t)1 * DH + j) * 128 + p * 64;
  const h2* rowG = wrowh + ((size_t)2 * DH + j) * 128 + p * 64;
  const h2* rowO = wrowh + ((size_t)3 * DH + j) * 128 + p * 64;

  // --- resident chunks 0..3 in named registers, pinned ---
#define DECLW(i) h8 WF_##i, WI_##i, WG_##i, WO_##i;
  CHR(DECLW)
#undef DECLW
#define LOADW(i) \
  WF_##i = *(const h8*)(const void*)(rowF + 4 * (i)); \
  WI_##i = *(const h8*)(const void*)(rowI + 4 * (i)); \
  WG_##i = *(const h8*)(const void*)(rowG + 4 * (i)); \
  WO_##i = *(const h8*)(const void*)(rowO + 4 * (i));
  CHR(LOADW)
#undef LOADW
#define PINW(i) \
  asm volatile("" : "+v"(WF_##i)); asm volatile("" : "+v"(WI_##i)); \
  asm volatile("" : "+v"(WG_##i)); asm volatile("" : "+v"(WO_##i));
  CHR(PINW)
#undef PINW

  // streaming bases: h8-index = (c-4)*2048 + gate*512 + tid
  const h8* sF = wstr + tid;
  const h8* sI = wstr + tid + 512;
  const h8* sG = wstr + tid + 1024;
  const h8* sO = wstr + tid + 1536;

  float creg = csrc[(size_t)b * DH + j];  // replicated across the pair
  if (tid < 128) {
    int pos = (tid < 64) ? tid : (HPAD + tid - 64);
    h2 hv;
    hv[0] = (_Float16)hsrc[(size_t)b * DH + 2 * tid];
    hv[1] = (_Float16)hsrc[(size_t)b * DH + 2 * tid + 1];
    hbuf0[pos] = hv;
  }
  __syncthreads();

  const size_t xstep = (size_t)NB * G4;
  const _Float16* xpA = Xg + (size_t)b * G4 + p * 512 + j;   // f or g
  const _Float16* xpB = xpA + 256;                           // i or o
  float xA = (float)xpA[0], xB = (float)xpB[0];
  float hlast = 0.f;

  for (int t = 0; t < Tc; ++t) {
    float xAn = 0.f, xBn = 0.f;
    if (t + 1 < Tc) {
      xAn = (float)xpA[(size_t)(t + 1) * xstep];
      xBn = (float)xpB[(size_t)(t + 1) * xstep];
    }
    const h2* hb = ((t & 1) ? hbuf1 : hbuf0) + hoff;

    float accF = p ? 0.f : xA;
    float accI = p ? 0.f : xB;
    float accG = p ? xA : 0.f;
    float accO = p ? xB : 0.f;

    h8 AF, AI, AG, AO, BF, BI, BG, BO;
#define LDGR(Gp, c) \
    Gp##F = sF[((c) - 4) * 2048]; Gp##I = sI[((c) - 4) * 2048]; \
    Gp##G = sG[((c) - 4) * 2048]; Gp##O = sO[((c) - 4) * 2048];
#define DOTG(FX, IX, GX, OX, c) { \
    h8 hv = *(const h8*)(const void*)(hb + 4 * (c)); \
    accF = fdot2(sl2(FX,0), sl2(hv,0), accF); \
    accF = fdot2(sl2(FX,1), sl2(hv,1), accF); \
    accF = fdot2(sl2(FX,2), sl2(hv,2), accF); \
    accF = fdot2(sl2(FX,3), sl2(hv,3), accF); \
    accI = fdot2(sl2(IX,0), sl2(hv,0), accI); \
    accI = fdot2(sl2(IX,1), sl2(hv,1), accI); \
    accI = fdot2(sl2(IX,2), sl2(hv,2), accI); \
    accI = fdot2(sl2(IX,3), sl2(hv,3), accI); \
    accG = fdot2(sl2(GX,0), sl2(hv,0), accG); \
    accG = fdot2(sl2(GX,1), sl2(hv,1), accG); \
    accG = fdot2(sl2(GX,2), sl2(hv,2), accG); \
    accG = fdot2(sl2(GX,3), sl2(hv,3), accG); \
    accO = fdot2(sl2(OX,0), sl2(hv,0), accO); \
    accO = fdot2(sl2(OX,1), sl2(hv,1), accO); \
    accO = fdot2(sl2(OX,2), sl2(hv,2), accO); \
    accO = fdot2(sl2(OX,3), sl2(hv,3), accO); }

    // issue first two streamed chunk-groups, then compute resident chunks
    LDGR(A, 4)
    LDGR(B, 5)
    DOTG(WF_0, WI_0, WG_0, WO_0, 0)
    DOTG(WF_1, WI_1, WG_1, WO_1, 1)
    DOTG(WF_2, WI_2, WG_2, WO_2, 2)
    DOTG(WF_3, WI_3, WG_3, WO_3, 3)
    // streamed chunks, depth-1 software pipeline
    DOTG(AF, AI, AG, AO, 4)  LDGR(A, 6)
    DOTG(BF, BI, BG, BO, 5)  LDGR(B, 7)
    DOTG(AF, AI, AG, AO, 6)  LDGR(A, 8)
    DOTG(BF, BI, BG, BO, 7)  LDGR(B, 9)
    DOTG(AF, AI, AG, AO, 8)  LDGR(A, 10)
    DOTG(BF, BI, BG, BO, 9)  LDGR(B, 11)
    DOTG(AF, AI, AG, AO, 10) LDGR(A, 12)
    DOTG(BF, BI, BG, BO, 11) LDGR(B, 13)
    DOTG(AF, AI, AG, AO, 12) LDGR(A, 14)
    DOTG(BF, BI, BG, BO, 13) LDGR(B, 15)
    DOTG(AF, AI, AG, AO, 14)
    DOTG(BF, BI, BG, BO, 15)
#undef LDGR
#undef DOTG

    // combine K-halves across the lane pair (DPP); both lanes get full sums
    accF += dpp_swap1(accF);
    accI += dpp_swap1(accI);
    accG += dpp_swap1(accG);
    accO += dpp_swap1(accO);

    float f_ = sigmoid_(accF);
    float i_ = sigmoid_(accI);
    float g_ = tanh_(accG);
    float o_ = sigmoid_(accO);

    creg = f_ * creg + i_ * g_;
    float hn = o_ * tanh_(creg);
    hlast = hn;
    if (p == 0) {
      out[((size_t)(t0 + t) * NB + b) * DH + j] = hn;
    } else {
      int pos = (j < 128) ? j : (2 * HPAD + (j - 128));
      ((_Float16*)((t & 1) ? hbuf0 : hbuf1))[pos] = (_Float16)hn;
    }
    __syncthreads();
    xA = xAn; xB = xBn;
  }

  if (p == 0) {
    hN[(size_t)b * DH + j] = hlast;
    cN[(size_t)b * DH + j] = creg;
  }
}

// ---------------------------------------------------------------------------
extern "C" void kernel_launch(void* const* d_in, const int* in_sizes, int n_in,
                              void* d_out, int out_size, void* d_ws, size_t ws_size,
                              hipStream_t stream) {
  if (n_in < 11) return;
  const float* x  = (const float*)d_in[0];
  const float* h0 = (const float*)d_in[1];
  const float* c0 = (const float*)d_in[2];
  const float* Wf = (const float*)d_in[3];
  const float* bf = (const float*)d_in[4];
  const float* Wi = (const float*)d_in[5];
  const float* bi = (const float*)d_in[6];
  const float* Wg = (const float*)d_in[7];
  const float* bg = (const float*)d_in[8];
  const float* Wo = (const float*)d_in[9];
  const float* bo = (const float*)d_in[10];

  float* out = (float*)d_out;
  float* hN = out + (size_t)T_STEPS * NB * DH;
  float* cN = hN + (size_t)NB * DH;

  // ws layout: [Xg: Tc*128KB][wxhT 512KB][wrowh 512KB][wstr 384KB]
  const size_t wxhBytes  = (size_t)128 * G4 * sizeof(h2);   // 512KB
  const size_t wrowBytes = (size_t)G4 * 128 * sizeof(h2);   // 512KB
  const size_t wstrBytes = (size_t)12 * 1024 * 2 * 16;      // 384KB
  const size_t fixedBytes = wxhBytes + wrowBytes + wstrBytes;
  size_t avail = (ws_size > fixedBytes + 512) ? ws_size - fixedBytes - 512 : 0;
  const size_t perT = (size_t)NB * G4 * 2;  // 128KB per time step
  int Tc = (int)(avail / perT);
  if (Tc > T_STEPS) Tc = T_STEPS;
  if (Tc < 1) Tc = 1;

  _Float16* Xg = (_Float16*)d_ws;
  size_t xgBytes = ((size_t)Tc * perT + 255) / 256 * 256;
  h2* wxhT  = (h2*)((char*)d_ws + xgBytes);
  h2* wrowh = (h2*)((char*)d_ws + xgBytes + wxhBytes);
  h2* wstr  = (h2*)((char*)d_ws + xgBytes + wxhBytes + wrowBytes);

  kconv_w<<<dim3(512), dim3(256), 0, stream>>>(Wf, Wi, Wg, Wo, wxhT, wrowh, wstr);

  for (int t0 = 0; t0 < T_STEPS; t0 += Tc) {
    int tc = (T_STEPS - t0 < Tc) ? (T_STEPS - t0) : Tc;
    kxgemm<<<dim3(tc * 4), dim3(256), 0, stream>>>(x, wxhT, bf, bi, bg, bo, Xg, t0);
    const float* hs = (t0 == 0) ? h0 : hN;
    const float* cs = (t0 == 0) ? c0 : cN;
    klstm<<<dim3(NB), dim3(512), 0, stream>>>(wrowh, (const h8*)wstr, Xg, hs, cs,
                                              out, hN, cN, t0, tc);
  }
}

// Round 13
// 2041.969 us; speedup vs baseline: 15.4949x; 1.5673x over previous
//
#include <hip/hip_runtime.h>
#include <cstdint>
#include <cstddef>

#define T_STEPS 1024
#define NB 64
#define DIN 256
#define DH 256
#define DW 512            // DIN + DH (row width of each W)
#define G4 1024           // 4*DH gate rows

typedef _Float16 h2 __attribute__((ext_vector_type(2)));
typedef _Float16 h4 __attribute__((ext_vector_type(4)));
typedef _Float16 h8 __attribute__((ext_vector_type(8)));
typedef float f4 __attribute__((ext_vector_type(4)));

static __device__ __forceinline__ h2 sl2(h8 v, int m) {
  h2 r; r[0] = v[2 * m]; r[1] = v[2 * m + 1]; return r;
}

static __device__ __forceinline__ float fdot2(h2 a, h2 b, float c) {
#if __has_builtin(__builtin_amdgcn_fdot2)
  return __builtin_amdgcn_fdot2(a, b, c, false);
#else
  return c + (float)a[0]*(float)b[0] + (float)a[1]*(float)b[1];
#endif
}

static __device__ __forceinline__ float rcp_(float x) {
#if __has_builtin(__builtin_amdgcn_rcpf)
  return __builtin_amdgcn_rcpf(x);
#else
  return 1.0f / x;
#endif
}

static __device__ __forceinline__ float sigmoid_(float x) {
  return rcp_(1.f + __expf(-x));
}
static __device__ __forceinline__ float tanh_(float x) {
  float e = __expf(2.f * x);
  return 1.f - 2.f * rcp_(e + 1.f);
}

// Pairwise lane swap (0<->1, ...) via DPP quad_perm [1,0,3,2] — pure VALU.
static __device__ __forceinline__ float dpp_swap1(float x) {
  int r = __builtin_amdgcn_update_dpp(0, __builtin_bit_cast(int, x),
                                      0xB1, 0xF, 0xF, true);
  return __builtin_bit_cast(float, r);
}

// ---------------------------------------------------------------------------
// Weight pre-conversion:
//  wxf[gr][k]   x-part  f16 row-major k-contig (MFMA B-operand, m97 pattern)
//  wrowh[gr][kp] h-part f16 row-major          (klstm)
// grid: 512 blocks (kp = bid>>2, gate = bid&3), 256 threads (j)
// ---------------------------------------------------------------------------
__global__ void kconv_w(const float* __restrict__ Wf, const float* __restrict__ Wi,
                        const float* __restrict__ Wg, const float* __restrict__ Wo,
                        h2* __restrict__ wxf, h2* __restrict__ wrowh) {
  int kp = blockIdx.x >> 2;
  int gate = blockIdx.x & 3;
  int j = threadIdx.x;
  const float* W = gate == 0 ? Wf : gate == 1 ? Wi : gate == 2 ? Wg : Wo;
  const float* row = W + (size_t)j * DW;
  h2 v; v[0] = (_Float16)row[2*kp]; v[1] = (_Float16)row[2*kp + 1];
  wxf[((size_t)gate * DH + j) * 128 + kp] = v;
  h2 u; u[0] = (_Float16)row[DIN + 2*kp]; u[1] = (_Float16)row[DIN + 2*kp + 1];
  wrowh[((size_t)gate * DH + j) * 128 + kp] = u;
}

// ---------------------------------------------------------------------------
// Phase 1 (MFMA): Xg = x . Wx^T + bias, stored in MFMA-NATIVE layout:
//   Xg[t_local][ idx ] , idx(gr,b) = (gr>>4)*1024 + (b>>2)*64 + (gr&15)*4 + (b&3)
// Block = (t = bid>>2, gate nb = bid&3) -> N-slice [nb*256, nb*256+256).
// 4 waves; wave w computes batch m-tile [w*16, w*16+16) x 256 gates.
// A-frag: x f32 loaded directly (+cvt to f16); lane l -> row l&15,
// k = (l>>4)*8..+8 contiguous (m92/m97-verified fragment pattern for *x32).
// B-frag: wxf row-major (B^T input). C/D: col=lane&15, row=(lane>>4)*4+reg
// (m89-verified) -> 4 acc regs = 4 consecutive batches = packed 8B store,
// perfectly coalesced. Zero LDS.
// ---------------------------------------------------------------------------
typedef float f32x4 __attribute__((ext_vector_type(4)));

__launch_bounds__(256, 1)
__global__ void kxgemm(const float* __restrict__ x,
                       const _Float16* __restrict__ wxf,
                       const float* __restrict__ bf, const float* __restrict__ bi,
                       const float* __restrict__ bg, const float* __restrict__ bo,
                       _Float16* __restrict__ Xg,
                       int t0) {
  int tid = threadIdx.x;
  int l = tid & 63;
  int w = tid >> 6;
  int tl = blockIdx.x >> 2;          // local t within chunk
  int nb = blockIdx.x & 3;           // gate
  int m0 = w * 16;
  int li = l & 15, lg = l >> 4;

  const float* aptr = x + ((size_t)(t0 + tl) * NB + m0 + li) * DIN + lg * 8;
  const _Float16* bptr = wxf + ((size_t)nb * 256 + li) * 256 + lg * 8;

  f32x4 acc[16];
#pragma unroll
  for (int nt = 0; nt < 16; ++nt) {
    acc[nt][0] = 0.f; acc[nt][1] = 0.f; acc[nt][2] = 0.f; acc[nt][3] = 0.f;
  }

  for (int ks = 0; ks < 8; ++ks) {
    f4 av0 = *(const f4*)(aptr + ks * 32);
    f4 av1 = *(const f4*)(aptr + ks * 32 + 4);
    h8 a;
    a[0] = (_Float16)av0[0]; a[1] = (_Float16)av0[1];
    a[2] = (_Float16)av0[2]; a[3] = (_Float16)av0[3];
    a[4] = (_Float16)av1[0]; a[5] = (_Float16)av1[1];
    a[6] = (_Float16)av1[2]; a[7] = (_Float16)av1[3];
#pragma unroll
    for (int nt = 0; nt < 16; ++nt) {
      h8 bb = *(const h8*)(bptr + (size_t)nt * 16 * 256 + ks * 32);
      acc[nt] = __builtin_amdgcn_mfma_f32_16x16x32_f16(a, bb, acc[nt], 0, 0, 0);
    }
  }

  const float* biasp = nb == 0 ? bf : nb == 1 ? bi : nb == 2 ? bg : bo;
  // store base: G = nb*16+nt ; q = b>>2 = w*4+lg ; idx = G*1024 + q*64 + li*4
  _Float16* ob = Xg + (size_t)tl * 65536 + (size_t)nb * 16384
               + (size_t)(w * 4 + lg) * 64 + li * 4;
#pragma unroll
  for (int nt = 0; nt < 16; ++nt) {
    float bv = biasp[nt * 16 + li];
    h4 o;
    o[0] = (_Float16)(acc[nt][0] + bv);
    o[1] = (_Float16)(acc[nt][1] + bv);
    o[2] = (_Float16)(acc[nt][2] + bv);
    o[3] = (_Float16)(acc[nt][3] + bv);
    *(h4*)(void*)(ob + (size_t)nt * 1024) = o;
  }
}

// ---------------------------------------------------------------------------
// Phase 2: sequential LSTM — r7-EXACT (proven 1722-1736us), except the two
// Xg address lines adapted to the MFMA-native Xg layout.
// ---------------------------------------------------------------------------
#define CH12(M) M(0) M(1) M(2) M(3) M(4) M(5) M(6) M(7) M(8) M(9) M(10) M(11)

#define HPAD 68   // h2 stride of one K-half in hbuf (64 + 4 skew)

__global__ __launch_bounds__(512, 1)
void klstm(const h2* __restrict__ wrowh,
           const _Float16* __restrict__ Xg,
           const float* __restrict__ hsrc, const float* __restrict__ csrc,
           float* __restrict__ out,
           float* __restrict__ hN, float* __restrict__ cN,
           int t0, int Tc) {
  __shared__ h8 wtail[16][512];        // 128KB: [row*4 + (chunk-12)][tid]
  __shared__ h2 hbuf[2][2 * HPAD];     // double-buffered h, halves skewed

  int tid = threadIdx.x;
  int b = blockIdx.x;
  int p = tid & 1;
  int j = tid >> 1;
  int hoff = p * HPAD;

  const h2* rowF = wrowh + ((size_t)0 * DH + j) * 128 + p * 64;
  const h2* rowI = wrowh + ((size_t)1 * DH + j) * 128 + p * 64;
  const h2* rowG = wrowh + ((size_t)2 * DH + j) * 128 + p * 64;
  const h2* rowO = wrowh + ((size_t)3 * DH + j) * 128 + p * 64;

#define DECLW(i) h8 WF_##i, WI_##i, WG_##i, WO_##i;
  CH12(DECLW)
#undef DECLW
#define LOADW(i) \
  WF_##i = *(const h8*)(const void*)(rowF + 4 * (i)); \
  WI_##i = *(const h8*)(const void*)(rowI + 4 * (i)); \
  WG_##i = *(const h8*)(const void*)(rowG + 4 * (i)); \
  WO_##i = *(const h8*)(const void*)(rowO + 4 * (i));
  CH12(LOADW)
#undef LOADW
#define PINW(i) \
  asm volatile("" : "+v"(WF_##i)); asm volatile("" : "+v"(WI_##i)); \
  asm volatile("" : "+v"(WG_##i)); asm volatile("" : "+v"(WO_##i));
  CH12(PINW)
#undef PINW

#pragma unroll
  for (int tt = 0; tt < 4; ++tt) {
    wtail[0  + tt][tid] = *(const h8*)(const void*)(rowF + 4 * (12 + tt));
    wtail[4  + tt][tid] = *(const h8*)(const void*)(rowI + 4 * (12 + tt));
    wtail[8  + tt][tid] = *(const h8*)(const void*)(rowG + 4 * (12 + tt));
    wtail[12 + tt][tid] = *(const h8*)(const void*)(rowO + 4 * (12 + tt));
  }

  float creg = csrc[(size_t)b * DH + j];
  if (tid < 128) {
    int pos = (tid < 64) ? tid : (HPAD + tid - 64);
    h2 hv;
    hv[0] = (_Float16)hsrc[(size_t)b * DH + 2 * tid];
    hv[1] = (_Float16)hsrc[(size_t)b * DH + 2 * tid + 1];
    hbuf[0][pos] = hv;
  }
  __syncthreads();

  const size_t xstep = (size_t)NB * G4;   // 65536 per t (unchanged)
  // MFMA-native Xg: idx(gr,b) = (gr>>4)*1024 + (b>>2)*64 + (gr&15)*4 + (b&3)
  // p=0 -> gates {f=0, i=1}; p=1 -> gates {g=2, o=3}; gate g row = g*256+j.
  size_t idxA = (size_t)((2 * p) * 16 + (j >> 4)) * 1024
              + (size_t)(b >> 2) * 64 + (j & 15) * 4 + (b & 3);
  const _Float16* xpA = Xg + idxA;          // gate 2p
  const _Float16* xpB = xpA + 16384;        // gate 2p+1
  float xA = (float)xpA[0], xB = (float)xpB[0];
  float hlast = 0.f;

  for (int t = 0; t < Tc; ++t) {
    float xAn = 0.f, xBn = 0.f;
    if (t + 1 < Tc) {
      xAn = (float)xpA[(size_t)(t + 1) * xstep];
      xBn = (float)xpB[(size_t)(t + 1) * xstep];
    }
    const h2* hb = hbuf[t & 1] + hoff;

    float accF = p ? 0.f : xA;
    float accI = p ? 0.f : xB;
    float accG = p ? xA : 0.f;
    float accO = p ? xB : 0.f;

#define DOTCH(i) { \
    h8 hv = *(const h8*)(const void*)(hb + 4 * (i)); \
    accF = fdot2(sl2(WF_##i,0), sl2(hv,0), accF); \
    accF = fdot2(sl2(WF_##i,1), sl2(hv,1), accF); \
    accF = fdot2(sl2(WF_##i,2), sl2(hv,2), accF); \
    accF = fdot2(sl2(WF_##i,3), sl2(hv,3), accF); \
    accI = fdot2(sl2(WI_##i,0), sl2(hv,0), accI); \
    accI = fdot2(sl2(WI_##i,1), sl2(hv,1), accI); \
    accI = fdot2(sl2(WI_##i,2), sl2(hv,2), accI); \
    accI = fdot2(sl2(WI_##i,3), sl2(hv,3), accI); \
    accG = fdot2(sl2(WG_##i,0), sl2(hv,0), accG); \
    accG = fdot2(sl2(WG_##i,1), sl2(hv,1), accG); \
    accG = fdot2(sl2(WG_##i,2), sl2(hv,2), accG); \
    accG = fdot2(sl2(WG_##i,3), sl2(hv,3), accG); \
    accO = fdot2(sl2(WO_##i,0), sl2(hv,0), accO); \
    accO = fdot2(sl2(WO_##i,1), sl2(hv,1), accO); \
    accO = fdot2(sl2(WO_##i,2), sl2(hv,2), accO); \
    accO = fdot2(sl2(WO_##i,3), sl2(hv,3), accO); }
    CH12(DOTCH)
#undef DOTCH
#pragma unroll
    for (int tt = 0; tt < 4; ++tt) {
      h8 hv = *(const h8*)(const void*)(hb + 4 * (12 + tt));
      h8 wf = wtail[0  + tt][tid];
      h8 wi = wtail[4  + tt][tid];
      h8 wg = wtail[8  + tt][tid];
      h8 wo = wtail[12 + tt][tid];
#pragma unroll
      for (int m = 0; m < 4; ++m) {
        accF = fdot2(sl2(wf, m), sl2(hv, m), accF);
        accI = fdot2(sl2(wi, m), sl2(hv, m), accI);
        accG = fdot2(sl2(wg, m), sl2(hv, m), accG);
        accO = fdot2(sl2(wo, m), sl2(hv, m), accO);
      }
    }

    accF += dpp_swap1(accF);
    accI += dpp_swap1(accI);
    accG += dpp_swap1(accG);
    accO += dpp_swap1(accO);

    float f_ = sigmoid_(accF);
    float i_ = sigmoid_(accI);
    float g_ = tanh_(accG);
    float o_ = sigmoid_(accO);

    creg = f_ * creg + i_ * g_;
    float hn = o_ * tanh_(creg);
    hlast = hn;
    if (p == 0) {
      out[((size_t)(t0 + t) * NB + b) * DH + j] = hn;
    } else {
      int pos = (j < 128) ? j : (2 * HPAD + (j - 128));
      ((_Float16*)hbuf[(t + 1) & 1])[pos] = (_Float16)hn;
    }
    __syncthreads();
    xA = xAn; xB = xBn;
  }

  if (p == 0) {
    hN[(size_t)b * DH + j] = hlast;
    cN[(size_t)b * DH + j] = creg;
  }
}

// ---------------------------------------------------------------------------
extern "C" void kernel_launch(void* const* d_in, const int* in_sizes, int n_in,
                              void* d_out, int out_size, void* d_ws, size_t ws_size,
                              hipStream_t stream) {
  if (n_in < 11) return;
  const float* x  = (const float*)d_in[0];
  const float* h0 = (const float*)d_in[1];
  const float* c0 = (const float*)d_in[2];
  const float* Wf = (const float*)d_in[3];
  const float* bf = (const float*)d_in[4];
  const float* Wi = (const float*)d_in[5];
  const float* bi = (const float*)d_in[6];
  const float* Wg = (const float*)d_in[7];
  const float* bg = (const float*)d_in[8];
  const float* Wo = (const float*)d_in[9];
  const float* bo = (const float*)d_in[10];

  float* out = (float*)d_out;
  float* hN = out + (size_t)T_STEPS * NB * DH;
  float* cN = hN + (size_t)NB * DH;

  // ws layout: [Xg ring: Tc*128KB][wxf 512KB][wrowh 512KB]
  const size_t wxfBytes  = (size_t)G4 * 128 * sizeof(h2);   // 512KB
  const size_t wrowBytes = (size_t)G4 * 128 * sizeof(h2);   // 512KB
  const size_t fixedBytes = wxfBytes + wrowBytes;
  size_t avail = (ws_size > fixedBytes + 512) ? ws_size - fixedBytes - 512 : 0;
  const size_t perT = (size_t)NB * G4 * 2;  // 128KB per time step
  int Tc = (int)(avail / perT);
  if (Tc > T_STEPS) Tc = T_STEPS;
  if (Tc < 1) Tc = 1;

  _Float16* Xg = (_Float16*)d_ws;
  size_t xgBytes = ((size_t)Tc * perT + 255) / 256 * 256;
  h2* wxf   = (h2*)((char*)d_ws + xgBytes);
  h2* wrowh = (h2*)((char*)d_ws + xgBytes + wxfBytes);

  kconv_w<<<dim3(512), dim3(256), 0, stream>>>(Wf, Wi, Wg, Wo, wxf, wrowh);

  for (int t0 = 0; t0 < T_STEPS; t0 += Tc) {
    int tc = (T_STEPS - t0 < Tc) ? (T_STEPS - t0) : Tc;
    kxgemm<<<dim3(tc * 4), dim3(256), 0, stream>>>(x, (const _Float16*)wxf,
                                                   bf, bi, bg, bo, Xg, t0);
    const float* hs = (t0 == 0) ? h0 : hN;
    const float* cs = (t0 == 0) ? c0 : cN;
    klstm<<<dim3(NB), dim3(512), 0, stream>>>(wrowh, Xg, hs, cs,
                                              out, hN, cN, t0, tc);
  }
}

// Round 14
// 1964.778 us; speedup vs baseline: 16.1037x; 1.0393x over previous
//
#include <hip/hip_runtime.h>
#include <cstdint>
#include <cstddef>

#define T_STEPS 1024
#define NB 64
#define DIN 256
#define DH 256
#define DW 512            // DIN + DH (row width of each W)
#define G4 1024           // 4*DH gate rows

typedef _Float16 h2 __attribute__((ext_vector_type(2)));
typedef _Float16 h4 __attribute__((ext_vector_type(4)));
typedef _Float16 h8 __attribute__((ext_vector_type(8)));
typedef float f4 __attribute__((ext_vector_type(4)));
typedef float f32x4 __attribute__((ext_vector_type(4)));

static __device__ __forceinline__ h2 sl2(h8 v, int m) {
  h2 r; r[0] = v[2 * m]; r[1] = v[2 * m + 1]; return r;
}

static __device__ __forceinline__ float fdot2(h2 a, h2 b, float c) {
#if __has_builtin(__builtin_amdgcn_fdot2)
  return __builtin_amdgcn_fdot2(a, b, c, false);
#else
  return c + (float)a[0]*(float)b[0] + (float)a[1]*(float)b[1];
#endif
}

static __device__ __forceinline__ float rcp_(float x) {
#if __has_builtin(__builtin_amdgcn_rcpf)
  return __builtin_amdgcn_rcpf(x);
#else
  return 1.0f / x;
#endif
}

static __device__ __forceinline__ float sigmoid_(float x) {
  return rcp_(1.f + __expf(-x));
}
static __device__ __forceinline__ float tanh_(float x) {
  float e = __expf(2.f * x);
  return 1.f - 2.f * rcp_(e + 1.f);
}

// Pairwise lane swap (0<->1, ...) via DPP quad_perm [1,0,3,2] — pure VALU.
static __device__ __forceinline__ float dpp_swap1(float x) {
  int r = __builtin_amdgcn_update_dpp(0, __builtin_bit_cast(int, x),
                                      0xB1, 0xF, 0xF, true);
  return __builtin_bit_cast(float, r);
}

// ---------------------------------------------------------------------------
// Weight pre-conversion:
//  wxf[gr][k]    x-part f16 row-major k-contig (MFMA B-operand)
//  wrowh[gr][kp] h-part f16 row-major          (klstm)
// ---------------------------------------------------------------------------
__global__ void kconv_w(const float* __restrict__ Wf, const float* __restrict__ Wi,
                        const float* __restrict__ Wg, const float* __restrict__ Wo,
                        h2* __restrict__ wxf, h2* __restrict__ wrowh) {
  int kp = blockIdx.x >> 2;
  int gate = blockIdx.x & 3;
  int j = threadIdx.x;
  const float* W = gate == 0 ? Wf : gate == 1 ? Wi : gate == 2 ? Wg : Wo;
  const float* row = W + (size_t)j * DW;
  h2 v; v[0] = (_Float16)row[2*kp]; v[1] = (_Float16)row[2*kp + 1];
  wxf[((size_t)gate * DH + j) * 128 + kp] = v;
  h2 u; u[0] = (_Float16)row[DIN + 2*kp]; u[1] = (_Float16)row[DIN + 2*kp + 1];
  wrowh[((size_t)gate * DH + j) * 128 + kp] = u;
}

// ---------------------------------------------------------------------------
// Phase 1 (MFMA v2): Xg[t][b][gr] = x . Wx^T + bias  — STANDARD layout out.
// Block = (tl = bid>>2, nb = bid&3); 4 waves, wave w = batch tile [16w,16w+16).
// A: x staged through LDS in FRAGMENT ORDER xsf[w][ks][lane] (lane-consecutive
//    16B writes & reads = conflict-free; global reads line-dense).
// B: wxf from L2, 64B fully-used lines per 16-lane row group (m97 B^T frag).
// Epilogue: acc -> per-wave LDS tile os[16][264] (264-stride => 2-way-free
//    b16 writes), read back lane-consecutive, store 512B-contiguous rows in
//    standard [t][b][gr] layout. Fragment mappings HW-verified in r13.
// ---------------------------------------------------------------------------
__launch_bounds__(256, 2)
__global__ void kxgemm(const float* __restrict__ x,
                       const _Float16* __restrict__ wxf,
                       const float* __restrict__ bf, const float* __restrict__ bi,
                       const float* __restrict__ bg, const float* __restrict__ bo,
                       _Float16* __restrict__ Xg,
                       int t0) {
  __shared__ h8 xsf[4][8][64];           // 32KB  A-frags [wave][ks][lane]
  __shared__ _Float16 os[4][16][264];    // 33.8KB per-wave C tiles (padded)

  int tid = threadIdx.x;
  int l = tid & 63;
  int w = tid >> 6;
  int li = l & 15, lg = l >> 4;
  int tl = blockIdx.x >> 2;
  int nb = blockIdx.x & 3;
  int m0 = w * 16;

  // --- stage A: 2048 h8 frags, 8 per thread, lane-consecutive LDS writes ---
#pragma unroll
  for (int i = 0; i < 8; ++i) {
    int hi = tid + 256 * i;            // h8 index 0..2047
    int sw  = hi >> 9;                 // wave tile
    int sks = (hi >> 6) & 7;           // ks
    int sl  = hi & 63;                 // lane slot
    int sli = sl & 15, slg = sl >> 4;
    const float* src = x + ((size_t)(t0 + tl) * NB + sw * 16 + sli) * DIN
                     + sks * 32 + slg * 8;
    f4 a0 = *(const f4*)src;
    f4 a1 = *(const f4*)(src + 4);
    h8 a;
    a[0] = (_Float16)a0[0]; a[1] = (_Float16)a0[1];
    a[2] = (_Float16)a0[2]; a[3] = (_Float16)a0[3];
    a[4] = (_Float16)a1[0]; a[5] = (_Float16)a1[1];
    a[6] = (_Float16)a1[2]; a[7] = (_Float16)a1[3];
    xsf[sw][sks][sl] = a;
  }
  __syncthreads();

  f32x4 acc[16];
#pragma unroll
  for (int nt = 0; nt < 16; ++nt) {
    acc[nt][0] = 0.f; acc[nt][1] = 0.f; acc[nt][2] = 0.f; acc[nt][3] = 0.f;
  }

  const _Float16* bptr = wxf + ((size_t)nb * 256 + li) * 256 + lg * 8;
  for (int ks = 0; ks < 8; ++ks) {
    h8 a = xsf[w][ks][l];
#pragma unroll
    for (int nt = 0; nt < 16; ++nt) {
      h8 bb = *(const h8*)(bptr + (size_t)nt * 16 * 256 + ks * 32);
      acc[nt] = __builtin_amdgcn_mfma_f32_16x16x32_f16(a, bb, acc[nt], 0, 0, 0);
    }
  }

  // --- epilogue: bias + transpose through per-wave LDS tile ---
  const float* biasp = nb == 0 ? bf : nb == 1 ? bi : nb == 2 ? bg : bo;
#pragma unroll
  for (int nt = 0; nt < 16; ++nt) {
    float bv = biasp[nt * 16 + li];
#pragma unroll
    for (int r = 0; r < 4; ++r)
      os[w][lg * 4 + r][nt * 16 + li] = (_Float16)(acc[nt][r] + bv);
  }
  // per-wave private tile: intra-wave RAW handled by waitcnt, no barrier.
  _Float16* og = Xg + (size_t)tl * 65536 + (size_t)m0 * 1024 + nb * 256;
#pragma unroll
  for (int it = 0; it < 8; ++it) {
    int i = l + 64 * it;
    int row = i >> 5, c8 = i & 31;
    h8 v = *(const h8*)(const void*)&os[w][row][c8 * 8];
    *(h8*)(void*)(og + (size_t)row * 1024 + c8 * 8) = v;
  }
}

// ---------------------------------------------------------------------------
// Phase 2: sequential LSTM — r7-EXACT (proven 1722-1736us, 0 conflicts).
// ---------------------------------------------------------------------------
#define CH12(M) M(0) M(1) M(2) M(3) M(4) M(5) M(6) M(7) M(8) M(9) M(10) M(11)

#define HPAD 68   // h2 stride of one K-half in hbuf (64 + 4 skew)

__global__ __launch_bounds__(512, 1)
void klstm(const h2* __restrict__ wrowh,
           const _Float16* __restrict__ Xg,
           const float* __restrict__ hsrc, const float* __restrict__ csrc,
           float* __restrict__ out,
           float* __restrict__ hN, float* __restrict__ cN,
           int t0, int Tc) {
  __shared__ h8 wtail[16][512];        // 128KB: [row*4 + (chunk-12)][tid]
  __shared__ h2 hbuf[2][2 * HPAD];     // double-buffered h, halves skewed

  int tid = threadIdx.x;
  int b = blockIdx.x;
  int p = tid & 1;
  int j = tid >> 1;
  int hoff = p * HPAD;

  const h2* rowF = wrowh + ((size_t)0 * DH + j) * 128 + p * 64;
  const h2* rowI = wrowh + ((size_t)1 * DH + j) * 128 + p * 64;
  const h2* rowG = wrowh + ((size_t)2 * DH + j) * 128 + p * 64;
  const h2* rowO = wrowh + ((size_t)3 * DH + j) * 128 + p * 64;

#define DECLW(i) h8 WF_##i, WI_##i, WG_##i, WO_##i;
  CH12(DECLW)
#undef DECLW
#define LOADW(i) \
  WF_##i = *(const h8*)(const void*)(rowF + 4 * (i)); \
  WI_##i = *(const h8*)(const void*)(rowI + 4 * (i)); \
  WG_##i = *(const h8*)(const void*)(rowG + 4 * (i)); \
  WO_##i = *(const h8*)(const void*)(rowO + 4 * (i));
  CH12(LOADW)
#undef LOADW
#define PINW(i) \
  asm volatile("" : "+v"(WF_##i)); asm volatile("" : "+v"(WI_##i)); \
  asm volatile("" : "+v"(WG_##i)); asm volatile("" : "+v"(WO_##i));
  CH12(PINW)
#undef PINW

#pragma unroll
  for (int tt = 0; tt < 4; ++tt) {
    wtail[0  + tt][tid] = *(const h8*)(const void*)(rowF + 4 * (12 + tt));
    wtail[4  + tt][tid] = *(const h8*)(const void*)(rowI + 4 * (12 + tt));
    wtail[8  + tt][tid] = *(const h8*)(const void*)(rowG + 4 * (12 + tt));
    wtail[12 + tt][tid] = *(const h8*)(const void*)(rowO + 4 * (12 + tt));
  }

  float creg = csrc[(size_t)b * DH + j];
  if (tid < 128) {
    int pos = (tid < 64) ? tid : (HPAD + tid - 64);
    h2 hv;
    hv[0] = (_Float16)hsrc[(size_t)b * DH + 2 * tid];
    hv[1] = (_Float16)hsrc[(size_t)b * DH + 2 * tid + 1];
    hbuf[0][pos] = hv;
  }
  __syncthreads();

  const size_t xstep = (size_t)NB * G4;
  const _Float16* xpA = Xg + (size_t)b * G4 + p * 512 + j;        // f or g
  const _Float16* xpB = xpA + 256;                                // i or o
  float xA = (float)xpA[0], xB = (float)xpB[0];
  float hlast = 0.f;

  for (int t = 0; t < Tc; ++t) {
    float xAn = 0.f, xBn = 0.f;
    if (t + 1 < Tc) {
      xAn = (float)xpA[(size_t)(t + 1) * xstep];
      xBn = (float)xpB[(size_t)(t + 1) * xstep];
    }
    const h2* hb = hbuf[t & 1] + hoff;

    float accF = p ? 0.f : xA;
    float accI = p ? 0.f : xB;
    float accG = p ? xA : 0.f;
    float accO = p ? xB : 0.f;

#define DOTCH(i) { \
    h8 hv = *(const h8*)(const void*)(hb + 4 * (i)); \
    accF = fdot2(sl2(WF_##i,0), sl2(hv,0), accF); \
    accF = fdot2(sl2(WF_##i,1), sl2(hv,1), accF); \
    accF = fdot2(sl2(WF_##i,2), sl2(hv,2), accF); \
    accF = fdot2(sl2(WF_##i,3), sl2(hv,3), accF); \
    accI = fdot2(sl2(WI_##i,0), sl2(hv,0), accI); \
    accI = fdot2(sl2(WI_##i,1), sl2(hv,1), accI); \
    accI = fdot2(sl2(WI_##i,2), sl2(hv,2), accI); \
    accI = fdot2(sl2(WI_##i,3), sl2(hv,3), accI); \
    accG = fdot2(sl2(WG_##i,0), sl2(hv,0), accG); \
    accG = fdot2(sl2(WG_##i,1), sl2(hv,1), accG); \
    accG = fdot2(sl2(WG_##i,2), sl2(hv,2), accG); \
    accG = fdot2(sl2(WG_##i,3), sl2(hv,3), accG); \
    accO = fdot2(sl2(WO_##i,0), sl2(hv,0), accO); \
    accO = fdot2(sl2(WO_##i,1), sl2(hv,1), accO); \
    accO = fdot2(sl2(WO_##i,2), sl2(hv,2), accO); \
    accO = fdot2(sl2(WO_##i,3), sl2(hv,3), accO); }
    CH12(DOTCH)
#undef DOTCH
#pragma unroll
    for (int tt = 0; tt < 4; ++tt) {
      h8 hv = *(const h8*)(const void*)(hb + 4 * (12 + tt));
      h8 wf = wtail[0  + tt][tid];
      h8 wi = wtail[4  + tt][tid];
      h8 wg = wtail[8  + tt][tid];
      h8 wo = wtail[12 + tt][tid];
#pragma unroll
      for (int m = 0; m < 4; ++m) {
        accF = fdot2(sl2(wf, m), sl2(hv, m), accF);
        accI = fdot2(sl2(wi, m), sl2(hv, m), accI);
        accG = fdot2(sl2(wg, m), sl2(hv, m), accG);
        accO = fdot2(sl2(wo, m), sl2(hv, m), accO);
      }
    }

    accF += dpp_swap1(accF);
    accI += dpp_swap1(accI);
    accG += dpp_swap1(accG);
    accO += dpp_swap1(accO);

    float f_ = sigmoid_(accF);
    float i_ = sigmoid_(accI);
    float g_ = tanh_(accG);
    float o_ = sigmoid_(accO);

    creg = f_ * creg + i_ * g_;
    float hn = o_ * tanh_(creg);
    hlast = hn;
    if (p == 0) {
      out[((size_t)(t0 + t) * NB + b) * DH + j] = hn;
    } else {
      int pos = (j < 128) ? j : (2 * HPAD + (j - 128));
      ((_Float16*)hbuf[(t + 1) & 1])[pos] = (_Float16)hn;
    }
    __syncthreads();
    xA = xAn; xB = xBn;
  }

  if (p == 0) {
    hN[(size_t)b * DH + j] = hlast;
    cN[(size_t)b * DH + j] = creg;
  }
}

// ---------------------------------------------------------------------------
extern "C" void kernel_launch(void* const* d_in, const int* in_sizes, int n_in,
                              void* d_out, int out_size, void* d_ws, size_t ws_size,
                              hipStream_t stream) {
  if (n_in < 11) return;
  const float* x  = (const float*)d_in[0];
  const float* h0 = (const float*)d_in[1];
  const float* c0 = (const float*)d_in[2];
  const float* Wf = (const float*)d_in[3];
  const float* bf = (const float*)d_in[4];
  const float* Wi = (const float*)d_in[5];
  const float* bi = (const float*)d_in[6];
  const float* Wg = (const float*)d_in[7];
  const float* bg = (const float*)d_in[8];
  const float* Wo = (const float*)d_in[9];
  const float* bo = (const float*)d_in[10];

  float* out = (float*)d_out;
  float* hN = out + (size_t)T_STEPS * NB * DH;
  float* cN = hN + (size_t)NB * DH;

  // ws layout: [Xg ring: Tc*128KB][wxf 512KB][wrowh 512KB]
  const size_t wxfBytes  = (size_t)G4 * 128 * sizeof(h2);   // 512KB
  const size_t wrowBytes = (size_t)G4 * 128 * sizeof(h2);   // 512KB
  const size_t fixedBytes = wxfBytes + wrowBytes;
  size_t avail = (ws_size > fixedBytes + 512) ? ws_size - fixedBytes - 512 : 0;
  const size_t perT = (size_t)NB * G4 * 2;  // 128KB per time step
  int Tc = (int)(avail / perT);
  if (Tc > T_STEPS) Tc = T_STEPS;
  if (Tc < 1) Tc = 1;

  _Float16* Xg = (_Float16*)d_ws;
  size_t xgBytes = ((size_t)Tc * perT + 255) / 256 * 256;
  h2* wxf   = (h2*)((char*)d_ws + xgBytes);
  h2* wrowh = (h2*)((char*)d_ws + xgBytes + wxfBytes);

  kconv_w<<<dim3(512), dim3(256), 0, stream>>>(Wf, Wi, Wg, Wo, wxf, wrowh);

  for (int t0 = 0; t0 < T_STEPS; t0 += Tc) {
    int tc = (T_STEPS - t0 < Tc) ? (T_STEPS - t0) : Tc;
    kxgemm<<<dim3(tc * 4), dim3(256), 0, stream>>>(x, (const _Float16*)wxf,
                                                   bf, bi, bg, bo, Xg, t0);
    const float* hs = (t0 == 0) ? h0 : hN;
    const float* cs = (t0 == 0) ? c0 : cN;
    klstm<<<dim3(NB), dim3(512), 0, stream>>>(wrowh, Xg, hs, cs,
                                              out, hN, cN, t0, tc);
  }
}

// Round 15
// 1796.636 us; speedup vs baseline: 17.6108x; 1.0936x over previous
//
#include <hip/hip_runtime.h>
#include <cstdint>
#include <cstddef>

#define T_STEPS 1024
#define NB 64
#define DIN 256
#define DH 256
#define DW 512            // DIN + DH (row width of each W)
#define G4 1024           // 4*DH gate rows

typedef _Float16 h2 __attribute__((ext_vector_type(2)));
typedef _Float16 h4 __attribute__((ext_vector_type(4)));
typedef _Float16 h8 __attribute__((ext_vector_type(8)));
typedef float f4 __attribute__((ext_vector_type(4)));
typedef float f32x4 __attribute__((ext_vector_type(4)));

static __device__ __forceinline__ h2 sl2(h8 v, int m) {
  h2 r; r[0] = v[2 * m]; r[1] = v[2 * m + 1]; return r;
}

static __device__ __forceinline__ float fdot2(h2 a, h2 b, float c) {
#if __has_builtin(__builtin_amdgcn_fdot2)
  return __builtin_amdgcn_fdot2(a, b, c, false);
#else
  return c + (float)a[0]*(float)b[0] + (float)a[1]*(float)b[1];
#endif
}

static __device__ __forceinline__ float rcp_(float x) {
#if __has_builtin(__builtin_amdgcn_rcpf)
  return __builtin_amdgcn_rcpf(x);
#else
  return 1.0f / x;
#endif
}

static __device__ __forceinline__ float sigmoid_(float x) {
  return rcp_(1.f + __expf(-x));
}
static __device__ __forceinline__ float tanh_(float x) {
  float e = __expf(2.f * x);
  return 1.f - 2.f * rcp_(e + 1.f);
}

// Pairwise lane swap (0<->1, ...) via DPP quad_perm [1,0,3,2] — pure VALU.
static __device__ __forceinline__ float dpp_swap1(float x) {
  int r = __builtin_amdgcn_update_dpp(0, __builtin_bit_cast(int, x),
                                      0xB1, 0xF, 0xF, true);
  return __builtin_bit_cast(float, r);
}

// ---------------------------------------------------------------------------
// Weight pre-conversion:
//  wxfs: x-part f16 in MFMA-staging order — per (gate nb, ks) a 16KB slab of
//        1024 h8 ordered [nt][lg][li]; h8idx = ((nb*8+ks)*16 + nt)*64 + lg*16 + li
//        (kxgemm: coalesced global reads + lane-consecutive LDS writes)
//  wrowh[gr][kp]: h-part f16 row-major (klstm)
// grid: 512 blocks (kp = bid>>2, gate = bid&3), 256 threads (j)
// ---------------------------------------------------------------------------
__global__ void kconv_w(const float* __restrict__ Wf, const float* __restrict__ Wi,
                        const float* __restrict__ Wg, const float* __restrict__ Wo,
                        h2* __restrict__ wxfs, h2* __restrict__ wrowh) {
  int kp = blockIdx.x >> 2;
  int gate = blockIdx.x & 3;
  int j = threadIdx.x;
  const float* W = gate == 0 ? Wf : gate == 1 ? Wi : gate == 2 ? Wg : Wo;
  const float* row = W + (size_t)j * DW;
  h2 v; v[0] = (_Float16)row[2*kp]; v[1] = (_Float16)row[2*kp + 1];
  // k = 2*kp: ks = kp>>4, lg = (kp>>2)&3, h2-slot = kp&3; li = j&15, nt = j>>4
  {
    int ks = kp >> 4, lg = (kp >> 2) & 3, slot = kp & 3;
    int nt = j >> 4, li = j & 15;
    size_t h8idx = (((size_t)gate * 8 + ks) * 16 + nt) * 64 + lg * 16 + li;
    wxfs[h8idx * 4 + slot] = v;
  }
  h2 u; u[0] = (_Float16)row[DIN + 2*kp]; u[1] = (_Float16)row[DIN + 2*kp + 1];
  wrowh[((size_t)gate * DH + j) * 128 + kp] = u;
}

// ---------------------------------------------------------------------------
// Phase 1 (MFMA v3): Xg[t][b][gr] = x . Wx^T + bias, standard layout out.
// Block = (tl = bid>>2, nb = bid&3); 4 waves = batch tiles.
// A: staged once in fragment order (r14, verified).
// B: staged per-ks into LDS, double-buffered — block-wide reuse cuts L2
//    traffic 4x and converts in-loop L2 loads to conflict-free ds_reads;
//    next-ks loads issue BEFORE the 16 MFMAs (latency hidden under compute).
// Epilogue: r14's per-wave LDS transpose (overlaps the pool after last
//    barrier), 512B-contiguous stores. All fragment maps HW-verified r13/r14.
// ---------------------------------------------------------------------------
__launch_bounds__(256, 2)
__global__ void kxgemm(const float* __restrict__ x,
                       const h8* __restrict__ wxfs,
                       const float* __restrict__ bf, const float* __restrict__ bi,
                       const float* __restrict__ bg, const float* __restrict__ bo,
                       _Float16* __restrict__ Xg,
                       int t0) {
  __shared__ char pool[65536];
  h8 (*xsf)[8][64] = (h8(*)[8][64])pool;               // 32KB A-frags
  h8 (*bs)[1024] = (h8(*)[1024])(pool + 32768);        // 2x16KB B slabs

  int tid = threadIdx.x;
  int l = tid & 63;
  int w = tid >> 6;
  int li = l & 15, lg = l >> 4;
  int tl = blockIdx.x >> 2;
  int nb = blockIdx.x & 3;
  int m0 = w * 16;

  // --- stage A: 2048 h8 frags, 8 per thread (r14 pattern) ---
#pragma unroll
  for (int i = 0; i < 8; ++i) {
    int hi = tid + 256 * i;
    int sw  = hi >> 9;
    int sks = (hi >> 6) & 7;
    int sl  = hi & 63;
    int sli = sl & 15, slg = sl >> 4;
    const float* src = x + ((size_t)(t0 + tl) * NB + sw * 16 + sli) * DIN
                     + sks * 32 + slg * 8;
    f4 a0 = *(const f4*)src;
    f4 a1 = *(const f4*)(src + 4);
    h8 a;
    a[0] = (_Float16)a0[0]; a[1] = (_Float16)a0[1];
    a[2] = (_Float16)a0[2]; a[3] = (_Float16)a0[3];
    a[4] = (_Float16)a1[0]; a[5] = (_Float16)a1[1];
    a[6] = (_Float16)a1[2]; a[7] = (_Float16)a1[3];
    xsf[sw][sks][sl] = a;
  }
  // --- stage B for ks=0: coalesced reads, lane-consecutive writes ---
  {
    const h8* wsrc = wxfs + (size_t)(nb * 8 + 0) * 1024;
#pragma unroll
    for (int i = 0; i < 4; ++i) bs[0][tid + 256 * i] = wsrc[tid + 256 * i];
  }
  __syncthreads();

  f32x4 acc[16];
#pragma unroll
  for (int nt = 0; nt < 16; ++nt) {
    acc[nt][0] = 0.f; acc[nt][1] = 0.f; acc[nt][2] = 0.f; acc[nt][3] = 0.f;
  }

  for (int ks = 0; ks < 8; ++ks) {
    int buf = ks & 1;
    h8 ld0, ld1, ld2, ld3;
    if (ks < 7) {   // issue next-slab loads before the MFMAs (latency cover)
      const h8* wn = wxfs + (size_t)(nb * 8 + ks + 1) * 1024;
      ld0 = wn[tid]; ld1 = wn[tid + 256]; ld2 = wn[tid + 512]; ld3 = wn[tid + 768];
    }
    h8 a = xsf[w][ks][l];
#pragma unroll
    for (int nt = 0; nt < 16; ++nt) {
      h8 bb = bs[buf][nt * 64 + l];
      acc[nt] = __builtin_amdgcn_mfma_f32_16x16x32_f16(a, bb, acc[nt], 0, 0, 0);
    }
    if (ks < 7) {
      h8* bt = bs[buf ^ 1];
      bt[tid] = ld0; bt[tid + 256] = ld1; bt[tid + 512] = ld2; bt[tid + 768] = ld3;
    }
    __syncthreads();
  }

  // --- epilogue: bias + per-wave LDS transpose (pool reuse after barrier) ---
  _Float16* osw = (_Float16*)(pool + (size_t)w * 8448);   // [16][264]
  const float* biasp = nb == 0 ? bf : nb == 1 ? bi : nb == 2 ? bg : bo;
#pragma unroll
  for (int nt = 0; nt < 16; ++nt) {
    float bv = biasp[nt * 16 + li];
#pragma unroll
    for (int r = 0; r < 4; ++r)
      osw[(lg * 4 + r) * 264 + nt * 16 + li] = (_Float16)(acc[nt][r] + bv);
  }
  _Float16* og = Xg + (size_t)tl * 65536 + (size_t)m0 * 1024 + nb * 256;
#pragma unroll
  for (int it = 0; it < 8; ++it) {
    int i = l + 64 * it;
    int row = i >> 5, c8 = i & 31;
    h8 v = *(const h8*)(const void*)&osw[row * 264 + c8 * 8];
    *(h8*)(void*)(og + (size_t)row * 1024 + c8 * 8) = v;
  }
}

// ---------------------------------------------------------------------------
// Phase 2: sequential LSTM — r7/r14-EXACT (proven 1722-1738us, 0 conflicts).
// ---------------------------------------------------------------------------
#define CH12(M) M(0) M(1) M(2) M(3) M(4) M(5) M(6) M(7) M(8) M(9) M(10) M(11)

#define HPAD 68   // h2 stride of one K-half in hbuf (64 + 4 skew)

__global__ __launch_bounds__(512, 1)
void klstm(const h2* __restrict__ wrowh,
           const _Float16* __restrict__ Xg,
           const float* __restrict__ hsrc, const float* __restrict__ csrc,
           float* __restrict__ out,
           float* __restrict__ hN, float* __restrict__ cN,
           int t0, int Tc) {
  __shared__ h8 wtail[16][512];        // 128KB: [row*4 + (chunk-12)][tid]
  __shared__ h2 hbuf[2][2 * HPAD];     // double-buffered h, halves skewed

  int tid = threadIdx.x;
  int b = blockIdx.x;
  int p = tid & 1;
  int j = tid >> 1;
  int hoff = p * HPAD;

  const h2* rowF = wrowh + ((size_t)0 * DH + j) * 128 + p * 64;
  const h2* rowI = wrowh + ((size_t)1 * DH + j) * 128 + p * 64;
  const h2* rowG = wrowh + ((size_t)2 * DH + j) * 128 + p * 64;
  const h2* rowO = wrowh + ((size_t)3 * DH + j) * 128 + p * 64;

#define DECLW(i) h8 WF_##i, WI_##i, WG_##i, WO_##i;
  CH12(DECLW)
#undef DECLW
#define LOADW(i) \
  WF_##i = *(const h8*)(const void*)(rowF + 4 * (i)); \
  WI_##i = *(const h8*)(const void*)(rowI + 4 * (i)); \
  WG_##i = *(const h8*)(const void*)(rowG + 4 * (i)); \
  WO_##i = *(const h8*)(const void*)(rowO + 4 * (i));
  CH12(LOADW)
#undef LOADW
#define PINW(i) \
  asm volatile("" : "+v"(WF_##i)); asm volatile("" : "+v"(WI_##i)); \
  asm volatile("" : "+v"(WG_##i)); asm volatile("" : "+v"(WO_##i));
  CH12(PINW)
#undef PINW

#pragma unroll
  for (int tt = 0; tt < 4; ++tt) {
    wtail[0  + tt][tid] = *(const h8*)(const void*)(rowF + 4 * (12 + tt));
    wtail[4  + tt][tid] = *(const h8*)(const void*)(rowI + 4 * (12 + tt));
    wtail[8  + tt][tid] = *(const h8*)(const void*)(rowG + 4 * (12 + tt));
    wtail[12 + tt][tid] = *(const h8*)(const void*)(rowO + 4 * (12 + tt));
  }

  float creg = csrc[(size_t)b * DH + j];
  if (tid < 128) {
    int pos = (tid < 64) ? tid : (HPAD + tid - 64);
    h2 hv;
    hv[0] = (_Float16)hsrc[(size_t)b * DH + 2 * tid];
    hv[1] = (_Float16)hsrc[(size_t)b * DH + 2 * tid + 1];
    hbuf[0][pos] = hv;
  }
  __syncthreads();

  const size_t xstep = (size_t)NB * G4;
  const _Float16* xpA = Xg + (size_t)b * G4 + p * 512 + j;        // f or g
  const _Float16* xpB = xpA + 256;                                // i or o
  float xA = (float)xpA[0], xB = (float)xpB[0];
  float hlast = 0.f;

  for (int t = 0; t < Tc; ++t) {
    float xAn = 0.f, xBn = 0.f;
    if (t + 1 < Tc) {
      xAn = (float)xpA[(size_t)(t + 1) * xstep];
      xBn = (float)xpB[(size_t)(t + 1) * xstep];
    }
    const h2* hb = hbuf[t & 1] + hoff;

    float accF = p ? 0.f : xA;
    float accI = p ? 0.f : xB;
    float accG = p ? xA : 0.f;
    float accO = p ? xB : 0.f;

#define DOTCH(i) { \
    h8 hv = *(const h8*)(const void*)(hb + 4 * (i)); \
    accF = fdot2(sl2(WF_##i,0), sl2(hv,0), accF); \
    accF = fdot2(sl2(WF_##i,1), sl2(hv,1), accF); \
    accF = fdot2(sl2(WF_##i,2), sl2(hv,2), accF); \
    accF = fdot2(sl2(WF_##i,3), sl2(hv,3), accF); \
    accI = fdot2(sl2(WI_##i,0), sl2(hv,0), accI); \
    accI = fdot2(sl2(WI_##i,1), sl2(hv,1), accI); \
    accI = fdot2(sl2(WI_##i,2), sl2(hv,2), accI); \
    accI = fdot2(sl2(WI_##i,3), sl2(hv,3), accI); \
    accG = fdot2(sl2(WG_##i,0), sl2(hv,0), accG); \
    accG = fdot2(sl2(WG_##i,1), sl2(hv,1), accG); \
    accG = fdot2(sl2(WG_##i,2), sl2(hv,2), accG); \
    accG = fdot2(sl2(WG_##i,3), sl2(hv,3), accG); \
    accO = fdot2(sl2(WO_##i,0), sl2(hv,0), accO); \
    accO = fdot2(sl2(WO_##i,1), sl2(hv,1), accO); \
    accO = fdot2(sl2(WO_##i,2), sl2(hv,2), accO); \
    accO = fdot2(sl2(WO_##i,3), sl2(hv,3), accO); }
    CH12(DOTCH)
#undef DOTCH
#pragma unroll
    for (int tt = 0; tt < 4; ++tt) {
      h8 hv = *(const h8*)(const void*)(hb + 4 * (12 + tt));
      h8 wf = wtail[0  + tt][tid];
      h8 wi = wtail[4  + tt][tid];
      h8 wg = wtail[8  + tt][tid];
      h8 wo = wtail[12 + tt][tid];
#pragma unroll
      for (int m = 0; m < 4; ++m) {
        accF = fdot2(sl2(wf, m), sl2(hv, m), accF);
        accI = fdot2(sl2(wi, m), sl2(hv, m), accI);
        accG = fdot2(sl2(wg, m), sl2(hv, m), accG);
        accO = fdot2(sl2(wo, m), sl2(hv, m), accO);
      }
    }

    accF += dpp_swap1(accF);
    accI += dpp_swap1(accI);
    accG += dpp_swap1(accG);
    accO += dpp_swap1(accO);

    float f_ = sigmoid_(accF);
    float i_ = sigmoid_(accI);
    float g_ = tanh_(accG);
    float o_ = sigmoid_(accO);

    creg = f_ * creg + i_ * g_;
    float hn = o_ * tanh_(creg);
    hlast = hn;
    if (p == 0) {
      out[((size_t)(t0 + t) * NB + b) * DH + j] = hn;
    } else {
      int pos = (j < 128) ? j : (2 * HPAD + (j - 128));
      ((_Float16*)hbuf[(t + 1) & 1])[pos] = (_Float16)hn;
    }
    __syncthreads();
    xA = xAn; xB = xBn;
  }

  if (p == 0) {
    hN[(size_t)b * DH + j] = hlast;
    cN[(size_t)b * DH + j] = creg;
  }
}

// ---------------------------------------------------------------------------
extern "C" void kernel_launch(void* const* d_in, const int* in_sizes, int n_in,
                              void* d_out, int out_size, void* d_ws, size_t ws_size,
                              hipStream_t stream) {
  if (n_in < 11) return;
  const float* x  = (const float*)d_in[0];
  const float* h0 = (const float*)d_in[1];
  const float* c0 = (const float*)d_in[2];
  const float* Wf = (const float*)d_in[3];
  const float* bf = (const float*)d_in[4];
  const float* Wi = (const float*)d_in[5];
  const float* bi = (const float*)d_in[6];
  const float* Wg = (const float*)d_in[7];
  const float* bg = (const float*)d_in[8];
  const float* Wo = (const float*)d_in[9];
  const float* bo = (const float*)d_in[10];

  float* out = (float*)d_out;
  float* hN = out + (size_t)T_STEPS * NB * DH;
  float* cN = hN + (size_t)NB * DH;

  // ws layout: [Xg ring: Tc*128KB][wxfs 512KB][wrowh 512KB]
  const size_t wxfBytes  = (size_t)G4 * 128 * sizeof(h2);   // 512KB
  const size_t wrowBytes = (size_t)G4 * 128 * sizeof(h2);   // 512KB
  const size_t fixedBytes = wxfBytes + wrowBytes;
  size_t avail = (ws_size > fixedBytes + 512) ? ws_size - fixedBytes - 512 : 0;
  const size_t perT = (size_t)NB * G4 * 2;  // 128KB per time step
  int Tc = (int)(avail / perT);
  if (Tc > T_STEPS) Tc = T_STEPS;
  if (Tc < 1) Tc = 1;

  _Float16* Xg = (_Float16*)d_ws;
  size_t xgBytes = ((size_t)Tc * perT + 255) / 256 * 256;
  h2* wxfs  = (h2*)((char*)d_ws + xgBytes);
  h2* wrowh = (h2*)((char*)d_ws + xgBytes + wxfBytes);

  kconv_w<<<dim3(512), dim3(256), 0, stream>>>(Wf, Wi, Wg, Wo, wxfs, wrowh);

  for (int t0 = 0; t0 < T_STEPS; t0 += Tc) {
    int tc = (T_STEPS - t0 < Tc) ? (T_STEPS - t0) : Tc;
    kxgemm<<<dim3(tc * 4), dim3(256), 0, stream>>>(x, (const h8*)wxfs,
                                                   bf, bi, bg, bo, Xg, t0);
    const float* hs = (t0 == 0) ? h0 : hN;
    const float* cs = (t0 == 0) ? c0 : cN;
    klstm<<<dim3(NB), dim3(512), 0, stream>>>(wrowh, Xg, hs, cs,
                                              out, hN, cN, t0, tc);
  }
}